// Round 1
// baseline (1384.341 us; speedup 1.0000x reference)
//
#include <hip/hip_runtime.h>
#include <math.h>

// ---------------------------------------------------------------------------
// Disentangler: 32 independent component-MLPs over sampled token rows, then
// dedup-masked segment-sum pooling.
//   x[16][4096][2048] fp32; first 2048 tokens/t are "nodes", rest "edges".
//   For comp c (0..15 node, 16..31 edge), rows r = rand_indices[c][0..999],
//   gathered token = x[r>>11][(r&2047) + (edge?2048:0)].
//   h = gelu_exact(row @ W1[c] + b1[c]) ; o = h @ W2[c] + b2[c]
//   pooled[c][t] = sum over UNIQUE sampled rows with r>>11==t of o, / 4096
//   out[t][c*1024 + :] = pooled[c][t]
// ---------------------------------------------------------------------------

typedef __attribute__((ext_vector_type(8))) short bf16x8;   // 8 bf16 (4 VGPRs)
typedef __attribute__((ext_vector_type(4))) float f32x4;    // MFMA acc

constexpr int TT    = 16;      // timestamps
constexpr int TOKN  = 4096;    // tokens per t
constexpr int DD    = 2048;    // input dim
constexpr int HH    = 2048;    // hidden dim
constexpr int CC    = 1024;    // out dim per comp
constexpr int LL    = 1000;    // samples per comp
constexpr int NCOMP = 32;
constexpr int MP    = 1024;    // padded sample rows (multiple of BM)
constexpr int BM = 128, BN = 128, BK = 64;
constexpr int MT  = MP / BM;   // 8 m-tiles
constexpr int NT1 = HH / BN;   // 16 n-tiles (gemm1)
constexpr int NT2 = CC / BN;   // 8  n-tiles (gemm2)

__device__ __forceinline__ short f2bf(float f) {   // fp32 -> bf16 RNE
  union { float f; unsigned u; } v; v.f = f;
  unsigned r = v.u + 0x7fffu + ((v.u >> 16) & 1u);
  return (short)(r >> 16);
}

// --------------------------- dedup ----------------------------------------
// keep[c][l] = 1.0 iff l is the unique representative of its sampled row.
__global__ void dedup_kernel(const int* __restrict__ ridx,
                             unsigned* __restrict__ bitmap,
                             float* __restrict__ keepf) {
  int comp = blockIdx.x;
  for (int l = threadIdx.x; l < MP; l += 256) {
    float kv = 0.0f;
    if (l < LL) {
      int r = ridx[comp * LL + l];
      unsigned bit = 1u << (r & 31);
      unsigned old = atomicOr(&bitmap[(comp << 10) + (r >> 5)], bit);
      kv = (old & bit) ? 0.0f : 1.0f;
    }
    keepf[(comp << 10) + l] = kv;
  }
}

// --------------------------- GEMM1: h = gelu(x_sel @ W1 + b1) --------------
__global__ __launch_bounds__(256) void gemm1_kernel(
    const float* __restrict__ x, const int* __restrict__ ridx,
    const float* __restrict__ nW1, const float* __restrict__ nb1,
    const float* __restrict__ eW1, const float* __restrict__ eb1,
    short* __restrict__ hbuf) {
  __shared__ short As[BM * BK];   // swizzled: elem (m,k) at [m*64 + ((k/8 ^ (m&7))*8 + k%8)]
  __shared__ short Bs[BN * BK];   // elem (n,k) likewise (holds W1^T tile)

  int bid  = blockIdx.x;
  int comp = bid / (MT * NT1);
  int rem  = bid % (MT * NT1);
  int mt = rem / NT1, nt = rem % NT1;
  bool isEdge = comp >= 16;
  int k16 = isEdge ? comp - 16 : comp;
  const float* W1 = (isEdge ? eW1 : nW1) + (size_t)k16 * DD * HH;
  const float* b1 = (isEdge ? eb1 : nb1) + (size_t)k16 * HH;
  int tokoff = isEdge ? (TOKN / 2) : 0;

  int tid = threadIdx.x;
  int am  = tid & 127;        // staging row (A: m, B: n)
  int akr = tid >> 7;         // staging k-chunk (0/1 -> 32 elems each)

  // gather source row (clamp padded rows m>=1000 to a valid row; unused later)
  int mglob = mt * BM + am;
  int mi = mglob < LL ? mglob : LL - 1;
  int r = ridx[comp * LL + mi];
  int trow = r >> 11, tok = (r & 2047) + tokoff;
  const float* arow = x + ((size_t)trow * TOKN + tok) * DD;
  const float* wcol = W1 + nt * BN + am;   // column am of the n-tile

  int lane = tid & 63, wid = tid >> 6;
  int wm = (wid >> 1) << 6, wn = (wid & 1) << 6;  // 2x2 waves of 64x64
  int lr = lane & 15, lg = lane >> 4;

  f32x4 acc[4][4] = {};

  for (int k0 = 0; k0 < DD; k0 += BK) {
    float a[32], b[32];
    const float* ab = arow + k0 + akr * 32;
#pragma unroll
    for (int i = 0; i < 8; ++i) {
      float4 v = *reinterpret_cast<const float4*>(ab + 4 * i);
      a[4*i] = v.x; a[4*i+1] = v.y; a[4*i+2] = v.z; a[4*i+3] = v.w;
    }
    const float* bb = wcol + (size_t)(k0 + akr * 32) * HH;
#pragma unroll
    for (int j = 0; j < 32; ++j) b[j] = bb[(size_t)j * HH];

    __syncthreads();   // prior iter's frag reads done before overwrite
#pragma unroll
    for (int g = 0; g < 4; ++g) {
      bf16x8 pk;
#pragma unroll
      for (int e = 0; e < 8; ++e) pk[e] = f2bf(a[g * 8 + e]);
      int gran = akr * 4 + g;
      *reinterpret_cast<bf16x8*>(&As[(am << 6) + ((gran ^ (am & 7)) << 3)]) = pk;
    }
#pragma unroll
    for (int g = 0; g < 4; ++g) {
      bf16x8 pk;
#pragma unroll
      for (int e = 0; e < 8; ++e) pk[e] = f2bf(b[g * 8 + e]);
      int gran = akr * 4 + g;
      *reinterpret_cast<bf16x8*>(&Bs[(am << 6) + ((gran ^ (am & 7)) << 3)]) = pk;
    }
    __syncthreads();

#pragma unroll
    for (int kk = 0; kk < 2; ++kk) {   // two K=32 mfma steps
      bf16x8 af[4], bfr[4];
#pragma unroll
      for (int i = 0; i < 4; ++i) {
        int row = wm + i * 16 + lr;
        int gran = kk * 4 + lg;
        af[i] = *reinterpret_cast<const bf16x8*>(&As[(row << 6) + ((gran ^ (row & 7)) << 3)]);
      }
#pragma unroll
      for (int j = 0; j < 4; ++j) {
        int row = wn + j * 16 + lr;
        int gran = kk * 4 + lg;
        bfr[j] = *reinterpret_cast<const bf16x8*>(&Bs[(row << 6) + ((gran ^ (row & 7)) << 3)]);
      }
#pragma unroll
      for (int i = 0; i < 4; ++i)
#pragma unroll
        for (int j = 0; j < 4; ++j)
          acc[i][j] = __builtin_amdgcn_mfma_f32_16x16x32_bf16(af[i], bfr[j], acc[i][j], 0, 0, 0);
    }
  }

  // epilogue: + b1, exact gelu, store bf16 h
  const float* b1p = b1 + nt * BN;
  short* hbase = hbuf + ((size_t)(comp * MP + mt * BM)) * HH + nt * BN;
#pragma unroll
  for (int i = 0; i < 4; ++i)
#pragma unroll
    for (int j = 0; j < 4; ++j) {
      int nl = wn + j * 16 + lr;
      float bias = b1p[nl];
#pragma unroll
      for (int rr = 0; rr < 4; ++rr) {
        int ml = wm + i * 16 + lg * 4 + rr;   // C/D layout: row=(lane>>4)*4+reg
        float v = acc[i][j][rr] + bias;
        float ge = 0.5f * v * (1.0f + erff(v * 0.70710678118654752f));
        hbase[(size_t)ml * HH + nl] = f2bf(ge);
      }
    }
}

// --------------------------- GEMM2: o = h @ W2 + b2, masked seg-reduce -----
__global__ __launch_bounds__(256) void gemm2_kernel(
    const short* __restrict__ hbuf, const int* __restrict__ ridx,
    const float* __restrict__ nW2, const float* __restrict__ nb2,
    const float* __restrict__ eW2, const float* __restrict__ eb2,
    const float* __restrict__ keepf, float* __restrict__ partial) {
  __shared__ short As[BM * BK];
  __shared__ short Bs[BN * BK];
  __shared__ float part[TT * BN];
  __shared__ int   tarr[BM];
  __shared__ float karr[BM];

  int bid  = blockIdx.x;
  int comp = bid / (MT * NT2);
  int rem  = bid % (MT * NT2);
  int mt = rem / NT2, nt = rem % NT2;
  bool isEdge = comp >= 16;
  int k16 = isEdge ? comp - 16 : comp;
  const float* W2 = (isEdge ? eW2 : nW2) + (size_t)k16 * HH * CC;
  const float* b2 = (isEdge ? eb2 : nb2) + (size_t)k16 * CC;

  int tid = threadIdx.x;
  int am = tid & 127, akr = tid >> 7;

  if (tid < BM) {
    int mglob = mt * BM + tid;
    int mi = mglob < LL ? mglob : LL - 1;
    int r2 = ridx[comp * LL + mi];
    tarr[tid] = r2 >> 11;
    karr[tid] = keepf[(comp << 10) + mglob];   // 0 for padded/duplicate rows
  }
  for (int e = tid; e < TT * BN; e += 256) part[e] = 0.0f;

  const short* harow = hbuf + ((size_t)(comp * MP + mt * BM + am)) * HH;
  const float* wcol  = W2 + nt * BN + am;

  int lane = tid & 63, wid = tid >> 6;
  int wm = (wid >> 1) << 6, wn = (wid & 1) << 6;
  int lr = lane & 15, lg = lane >> 4;

  f32x4 acc[4][4] = {};

  for (int k0 = 0; k0 < HH; k0 += BK) {
    bf16x8 av[4];
    float b[32];
#pragma unroll
    for (int g = 0; g < 4; ++g)
      av[g] = *reinterpret_cast<const bf16x8*>(&harow[k0 + akr * 32 + g * 8]);
    const float* bb = wcol + (size_t)(k0 + akr * 32) * CC;
#pragma unroll
    for (int j = 0; j < 32; ++j) b[j] = bb[(size_t)j * CC];

    __syncthreads();
#pragma unroll
    for (int g = 0; g < 4; ++g) {
      int gran = akr * 4 + g;
      *reinterpret_cast<bf16x8*>(&As[(am << 6) + ((gran ^ (am & 7)) << 3)]) = av[g];
    }
#pragma unroll
    for (int g = 0; g < 4; ++g) {
      bf16x8 pk;
#pragma unroll
      for (int e = 0; e < 8; ++e) pk[e] = f2bf(b[g * 8 + e]);
      int gran = akr * 4 + g;
      *reinterpret_cast<bf16x8*>(&Bs[(am << 6) + ((gran ^ (am & 7)) << 3)]) = pk;
    }
    __syncthreads();

#pragma unroll
    for (int kk = 0; kk < 2; ++kk) {
      bf16x8 af[4], bfr[4];
#pragma unroll
      for (int i = 0; i < 4; ++i) {
        int row = wm + i * 16 + lr;
        int gran = kk * 4 + lg;
        af[i] = *reinterpret_cast<const bf16x8*>(&As[(row << 6) + ((gran ^ (row & 7)) << 3)]);
      }
#pragma unroll
      for (int j = 0; j < 4; ++j) {
        int row = wn + j * 16 + lr;
        int gran = kk * 4 + lg;
        bfr[j] = *reinterpret_cast<const bf16x8*>(&Bs[(row << 6) + ((gran ^ (row & 7)) << 3)]);
      }
#pragma unroll
      for (int i = 0; i < 4; ++i)
#pragma unroll
        for (int j = 0; j < 4; ++j)
          acc[i][j] = __builtin_amdgcn_mfma_f32_16x16x32_bf16(af[i], bfr[j], acc[i][j], 0, 0, 0);
    }
  }

  // epilogue: (+b2) * keep, reduce rows by timestamp into LDS, store partial
  const float* b2p = b2 + nt * BN;
#pragma unroll
  for (int i = 0; i < 4; ++i)
#pragma unroll
    for (int j = 0; j < 4; ++j) {
      int nl = wn + j * 16 + lr;
      float bias = b2p[nl];
#pragma unroll
      for (int rr = 0; rr < 4; ++rr) {
        int ml = wm + i * 16 + lg * 4 + rr;
        float v = (acc[i][j][rr] + bias) * karr[ml];
        atomicAdd(&part[tarr[ml] * BN + nl], v);
      }
    }
  __syncthreads();
  float* pout = partial + ((size_t)(comp * MT + mt)) * TT * CC + nt * BN;
  for (int e = tid; e < TT * BN; e += 256) {
    int t2 = e >> 7, c = e & 127;
    pout[(size_t)t2 * CC + c] = part[e];
  }
}

// --------------------------- final reduce over m-tiles ---------------------
__global__ void reduce_kernel(const float* __restrict__ partial,
                              float* __restrict__ out) {
  int idx = blockIdx.x * 256 + threadIdx.x;     // = t*32768 + comp*1024 + c
  int c    = idx & (CC - 1);
  int comp = (idx >> 10) & (NCOMP - 1);
  int t    = idx >> 15;
  float s = 0.0f;
#pragma unroll
  for (int mt = 0; mt < MT; ++mt)
    s += partial[(((size_t)(comp * MT + mt)) * TT + t) * CC + c];
  out[idx] = s * (1.0f / 4096.0f);
}

// ---------------------------------------------------------------------------
extern "C" void kernel_launch(void* const* d_in, const int* in_sizes, int n_in,
                              void* d_out, int out_size, void* d_ws, size_t ws_size,
                              hipStream_t stream) {
  const float* x    = (const float*)d_in[0];
  const int*   ridx = (const int*)d_in[3];
  const float* nW1  = (const float*)d_in[4];
  const float* nb1  = (const float*)d_in[5];
  const float* nW2  = (const float*)d_in[6];
  const float* nb2  = (const float*)d_in[7];
  const float* eW1  = (const float*)d_in[8];
  const float* eb1  = (const float*)d_in[9];
  const float* eW2  = (const float*)d_in[10];
  const float* eb2  = (const float*)d_in[11];
  float* out = (float*)d_out;

  // ws layout: h bf16 [32][1024][2048] | bitmap [32][1024]u32 | keep [32][1024]f32
  //            | partial [32][8][16][1024]f32   (total ~151 MB)
  char* ws = (char*)d_ws;
  short* hbuf = (short*)ws;
  size_t off = (size_t)NCOMP * MP * HH * sizeof(short);
  unsigned* bitmap = (unsigned*)(ws + off); off += (size_t)NCOMP * 1024 * 4;
  float* keepf     = (float*)(ws + off);    off += (size_t)NCOMP * 1024 * 4;
  float* partial   = (float*)(ws + off);

  hipMemsetAsync(bitmap, 0, NCOMP * 1024 * 4, stream);
  dedup_kernel<<<NCOMP, 256, 0, stream>>>(ridx, bitmap, keepf);
  gemm1_kernel<<<NCOMP * MT * NT1, 256, 0, stream>>>(x, ridx, nW1, nb1, eW1, eb1, hbuf);
  gemm2_kernel<<<NCOMP * MT * NT2, 256, 0, stream>>>(hbuf, ridx, nW2, nb2, eW2, eb2, keepf, partial);
  reduce_kernel<<<out_size / 256, 256, 0, stream>>>(partial, out);
}

// Round 2
// 1259.265 us; speedup vs baseline: 1.0993x; 1.0993x over previous
//
#include <hip/hip_runtime.h>
#include <math.h>

// ---------------------------------------------------------------------------
// Disentangler: 32 independent component-MLPs over sampled token rows, then
// dedup-masked segment-sum pooling.
//   x[16][4096][2048] fp32; first 2048 tokens/t are "nodes", rest "edges".
//   For comp c (0..15 node, 16..31 edge), rows r = rand_indices[c][0..999],
//   gathered token = x[r>>11][(r&2047) + (edge?2048:0)].
//   h = gelu_exact(row @ W1[c] + b1[c]) ; o = h @ W2[c] + b2[c]
//   pooled[c][t] = sum over UNIQUE sampled rows with r>>11==t of o, / 4096
//   out[t][c*1024 + :] = pooled[c][t]
// ---------------------------------------------------------------------------

typedef __attribute__((ext_vector_type(8))) short bf16x8;   // 8 bf16 (4 VGPRs)
typedef __attribute__((ext_vector_type(4))) float f32x4;    // MFMA acc

constexpr int TT    = 16;      // timestamps
constexpr int TOKN  = 4096;    // tokens per t
constexpr int DD    = 2048;    // input dim
constexpr int HH    = 2048;    // hidden dim
constexpr int CC    = 1024;    // out dim per comp
constexpr int LL    = 1000;    // samples per comp
constexpr int NCOMP = 32;
constexpr int MP    = 1024;    // padded sample rows (multiple of BM)
constexpr int BM = 128, BN = 128, BK = 64;
constexpr int MT  = MP / BM;   // 8 m-tiles
constexpr int NT1 = HH / BN;   // 16 n-tiles (gemm1)
constexpr int NT2 = CC / BN;   // 8  n-tiles (gemm2)

__device__ __forceinline__ short f2bf(float f) {   // native RNE cast
  __bf16 h = (__bf16)f;                            // -> v_cvt_pk_bf16_f32
  return *reinterpret_cast<short*>(&h);
}

// LDS tile: [row][8 granules of 8 bf16], granule slot XOR-swizzled.
// s(row) = (row&7) ^ ((row>>2)&3): uniform bank-quad spread for BOTH the
// 4-strided B writer rows and the 16-consecutive fragment-reader rows.
__device__ __forceinline__ int sw(int row, int gran) {
  int s = (row & 7) ^ ((row >> 2) & 3);
  return (row << 6) + ((gran ^ s) << 3);
}

// --------------------------- dedup ----------------------------------------
__global__ void dedup_kernel(const int* __restrict__ ridx,
                             unsigned* __restrict__ bitmap,
                             float* __restrict__ keepf) {
  int comp = blockIdx.x;
  for (int l = threadIdx.x; l < MP; l += 256) {
    float kv = 0.0f;
    if (l < LL) {
      int r = ridx[comp * LL + l];
      unsigned bit = 1u << (r & 31);
      unsigned old = atomicOr(&bitmap[(comp << 10) + (r >> 5)], bit);
      kv = (old & bit) ? 0.0f : 1.0f;
    }
    keepf[(comp << 10) + l] = kv;
  }
}

// --------------------------- GEMM1: h = gelu(x_sel @ W1 + b1) --------------
__global__ __launch_bounds__(256, 2) void gemm1_kernel(
    const float* __restrict__ x, const int* __restrict__ ridx,
    const float* __restrict__ nW1, const float* __restrict__ nb1,
    const float* __restrict__ eW1, const float* __restrict__ eb1,
    short* __restrict__ hbuf) {
  __shared__ short As[BM * BK];
  __shared__ short Bs[BN * BK];

  int bid  = blockIdx.x;
  int comp = bid / (MT * NT1);
  int rem  = bid % (MT * NT1);
  int mt = rem / NT1, nt = rem % NT1;
  bool isEdge = comp >= 16;
  int k16 = isEdge ? comp - 16 : comp;
  const float* W1 = (isEdge ? eW1 : nW1) + (size_t)k16 * DD * HH;
  const float* b1 = (isEdge ? eb1 : nb1) + (size_t)k16 * HH;
  int tokoff = isEdge ? (TOKN / 2) : 0;

  int tid = threadIdx.x;
  // A staging: thread (am, akr) loads 32 consecutive k of gathered row am
  int am  = tid & 127;
  int akr = tid >> 7;
  // B staging: thread (tn, tkb) loads a 8k x 4n block of W1 (row-major reads)
  int tn  = tid & 31;
  int tkb = tid >> 5;          // k-granule 0..7
  int bn0 = tn * 4;

  int mglob = mt * BM + am;
  int mi = mglob < LL ? mglob : LL - 1;
  int r = ridx[comp * LL + mi];
  int trow = r >> 11, tok = (r & 2047) + tokoff;
  const float* arow = x + ((size_t)trow * TOKN + tok) * DD;
  const float* bptr = W1 + nt * BN + bn0;

  int lane = tid & 63, wid = tid >> 6;
  int wm = (wid >> 1) << 6, wn = (wid & 1) << 6;   // 2x2 waves of 64x64
  int lr = lane & 15, lg = lane >> 4;

  float4 aR[8], bR[8];
  auto loadAB = [&](int k0) {
    const float* ab = arow + k0 + akr * 32;
#pragma unroll
    for (int i = 0; i < 8; ++i)
      aR[i] = *reinterpret_cast<const float4*>(ab + 4 * i);
    const float* bb = bptr + (size_t)(k0 + tkb * 8) * HH;
#pragma unroll
    for (int i = 0; i < 8; ++i)
      bR[i] = *reinterpret_cast<const float4*>(bb + (size_t)i * HH);
  };

  loadAB(0);
  f32x4 acc[4][4] = {};

  for (int k0 = 0; k0 < DD; k0 += BK) {
    __syncthreads();   // prior iter's fragment reads done before overwrite
    // A: 4 granules of 8 consecutive k for row am
#pragma unroll
    for (int g = 0; g < 4; ++g) {
      bf16x8 pk;
#pragma unroll
      for (int e = 0; e < 8; ++e)
        pk[e] = f2bf((&aR[2 * g + (e >> 2)].x)[e & 3]);
      *reinterpret_cast<bf16x8*>(&As[sw(am, akr * 4 + g)]) = pk;
    }
    // B: register transpose -> per column j, granule tkb (k=tkb*8..+7)
#pragma unroll
    for (int j = 0; j < 4; ++j) {
      bf16x8 pk;
#pragma unroll
      for (int i = 0; i < 8; ++i)
        pk[i] = f2bf((&bR[i].x)[j]);
      *reinterpret_cast<bf16x8*>(&Bs[sw(bn0 + j, tkb)]) = pk;
    }
    __syncthreads();

    if (k0 + BK < DD) loadAB(k0 + BK);   // prefetch: latency hides under MFMA

#pragma unroll
    for (int kk = 0; kk < 2; ++kk) {
      bf16x8 af[4], bfr[4];
#pragma unroll
      for (int i = 0; i < 4; ++i)
        af[i] = *reinterpret_cast<const bf16x8*>(&As[sw(wm + i * 16 + lr, kk * 4 + lg)]);
#pragma unroll
      for (int j = 0; j < 4; ++j)
        bfr[j] = *reinterpret_cast<const bf16x8*>(&Bs[sw(wn + j * 16 + lr, kk * 4 + lg)]);
#pragma unroll
      for (int i = 0; i < 4; ++i)
#pragma unroll
        for (int j = 0; j < 4; ++j)
          acc[i][j] = __builtin_amdgcn_mfma_f32_16x16x32_bf16(af[i], bfr[j], acc[i][j], 0, 0, 0);
    }
  }

  // epilogue: + b1, exact gelu, store bf16 h
  const float* b1p = b1 + nt * BN;
  short* hbase = hbuf + ((size_t)(comp * MP + mt * BM)) * HH + nt * BN;
#pragma unroll
  for (int i = 0; i < 4; ++i)
#pragma unroll
    for (int j = 0; j < 4; ++j) {
      int nl = wn + j * 16 + lr;
      float bias = b1p[nl];
#pragma unroll
      for (int rr = 0; rr < 4; ++rr) {
        int ml = wm + i * 16 + lg * 4 + rr;   // C/D: row=(lane>>4)*4+reg
        float v = acc[i][j][rr] + bias;
        float ge = 0.5f * v * (1.0f + erff(v * 0.70710678118654752f));
        hbase[(size_t)ml * HH + nl] = f2bf(ge);
      }
    }
}

// --------------------------- GEMM2: o = h @ W2 + b2, masked seg-reduce -----
__global__ __launch_bounds__(256, 2) void gemm2_kernel(
    const short* __restrict__ hbuf, const int* __restrict__ ridx,
    const float* __restrict__ nW2, const float* __restrict__ nb2,
    const float* __restrict__ eW2, const float* __restrict__ eb2,
    const float* __restrict__ keepf, float* __restrict__ partial) {
  __shared__ short As[BM * BK];
  __shared__ short Bs[BN * BK];
  __shared__ float part[TT * BN];
  __shared__ int   tarr[BM];
  __shared__ float karr[BM];

  int bid  = blockIdx.x;
  int comp = bid / (MT * NT2);
  int rem  = bid % (MT * NT2);
  int mt = rem / NT2, nt = rem % NT2;
  bool isEdge = comp >= 16;
  int k16 = isEdge ? comp - 16 : comp;
  const float* W2 = (isEdge ? eW2 : nW2) + (size_t)k16 * HH * CC;
  const float* b2 = (isEdge ? eb2 : nb2) + (size_t)k16 * CC;

  int tid = threadIdx.x;
  int am = tid & 127, akr = tid >> 7;
  int tn = tid & 31, tkb = tid >> 5;
  int bn0 = tn * 4;

  if (tid < BM) {
    int mglob = mt * BM + tid;
    int mi = mglob < LL ? mglob : LL - 1;
    int r2 = ridx[comp * LL + mi];
    tarr[tid] = r2 >> 11;
    karr[tid] = keepf[(comp << 10) + mglob];   // 0 for padded/duplicate rows
  }
  for (int e = tid; e < TT * BN; e += 256) part[e] = 0.0f;

  const short* harow = hbuf + ((size_t)(comp * MP + mt * BM + am)) * HH;
  const float* bptr  = W2 + nt * BN + bn0;

  int lane = tid & 63, wid = tid >> 6;
  int wm = (wid >> 1) << 6, wn = (wid & 1) << 6;
  int lr = lane & 15, lg = lane >> 4;

  bf16x8 aR[4];
  float4 bR[8];
  auto loadAB = [&](int k0) {
#pragma unroll
    for (int g = 0; g < 4; ++g)
      aR[g] = *reinterpret_cast<const bf16x8*>(&harow[k0 + akr * 32 + g * 8]);
    const float* bb = bptr + (size_t)(k0 + tkb * 8) * CC;
#pragma unroll
    for (int i = 0; i < 8; ++i)
      bR[i] = *reinterpret_cast<const float4*>(bb + (size_t)i * CC);
  };

  loadAB(0);
  f32x4 acc[4][4] = {};

  for (int k0 = 0; k0 < HH; k0 += BK) {
    __syncthreads();
#pragma unroll
    for (int g = 0; g < 4; ++g)
      *reinterpret_cast<bf16x8*>(&As[sw(am, akr * 4 + g)]) = aR[g];
#pragma unroll
    for (int j = 0; j < 4; ++j) {
      bf16x8 pk;
#pragma unroll
      for (int i = 0; i < 8; ++i)
        pk[i] = f2bf((&bR[i].x)[j]);
      *reinterpret_cast<bf16x8*>(&Bs[sw(bn0 + j, tkb)]) = pk;
    }
    __syncthreads();

    if (k0 + BK < HH) loadAB(k0 + BK);

#pragma unroll
    for (int kk = 0; kk < 2; ++kk) {
      bf16x8 af[4], bfr[4];
#pragma unroll
      for (int i = 0; i < 4; ++i)
        af[i] = *reinterpret_cast<const bf16x8*>(&As[sw(wm + i * 16 + lr, kk * 4 + lg)]);
#pragma unroll
      for (int j = 0; j < 4; ++j)
        bfr[j] = *reinterpret_cast<const bf16x8*>(&Bs[sw(wn + j * 16 + lr, kk * 4 + lg)]);
#pragma unroll
      for (int i = 0; i < 4; ++i)
#pragma unroll
        for (int j = 0; j < 4; ++j)
          acc[i][j] = __builtin_amdgcn_mfma_f32_16x16x32_bf16(af[i], bfr[j], acc[i][j], 0, 0, 0);
    }
  }

  // epilogue: (+b2) * keep, reduce rows by timestamp into LDS, store partial
  const float* b2p = b2 + nt * BN;
#pragma unroll
  for (int i = 0; i < 4; ++i)
#pragma unroll
    for (int j = 0; j < 4; ++j) {
      int nl = wn + j * 16 + lr;
      float bias = b2p[nl];
#pragma unroll
      for (int rr = 0; rr < 4; ++rr) {
        int ml = wm + i * 16 + lg * 4 + rr;
        float v = (acc[i][j][rr] + bias) * karr[ml];
        atomicAdd(&part[tarr[ml] * BN + nl], v);
      }
    }
  __syncthreads();
  float* pout = partial + ((size_t)(comp * MT + mt)) * TT * CC + nt * BN;
  for (int e = tid; e < TT * BN; e += 256) {
    int t2 = e >> 7, c = e & 127;
    pout[(size_t)t2 * CC + c] = part[e];
  }
}

// --------------------------- final reduce over m-tiles ---------------------
__global__ void reduce_kernel(const float* __restrict__ partial,
                              float* __restrict__ out) {
  int idx = blockIdx.x * 256 + threadIdx.x;     // = t*32768 + comp*1024 + c
  int c    = idx & (CC - 1);
  int comp = (idx >> 10) & (NCOMP - 1);
  int t    = idx >> 15;
  float s = 0.0f;
#pragma unroll
  for (int mt = 0; mt < MT; ++mt)
    s += partial[(((size_t)(comp * MT + mt)) * TT + t) * CC + c];
  out[idx] = s * (1.0f / 4096.0f);
}

// ---------------------------------------------------------------------------
extern "C" void kernel_launch(void* const* d_in, const int* in_sizes, int n_in,
                              void* d_out, int out_size, void* d_ws, size_t ws_size,
                              hipStream_t stream) {
  const float* x    = (const float*)d_in[0];
  const int*   ridx = (const int*)d_in[3];
  const float* nW1  = (const float*)d_in[4];
  const float* nb1  = (const float*)d_in[5];
  const float* nW2  = (const float*)d_in[6];
  const float* nb2  = (const float*)d_in[7];
  const float* eW1  = (const float*)d_in[8];
  const float* eb1  = (const float*)d_in[9];
  const float* eW2  = (const float*)d_in[10];
  const float* eb2  = (const float*)d_in[11];
  float* out = (float*)d_out;

  // ws layout: h bf16 [32][1024][2048] | bitmap [32][1024]u32 | keep [32][1024]f32
  //            | partial [32][8][16][1024]f32   (total ~151 MB)
  char* ws = (char*)d_ws;
  short* hbuf = (short*)ws;
  size_t off = (size_t)NCOMP * MP * HH * sizeof(short);
  unsigned* bitmap = (unsigned*)(ws + off); off += (size_t)NCOMP * 1024 * 4;
  float* keepf     = (float*)(ws + off);    off += (size_t)NCOMP * 1024 * 4;
  float* partial   = (float*)(ws + off);

  hipMemsetAsync(bitmap, 0, NCOMP * 1024 * 4, stream);
  dedup_kernel<<<NCOMP, 256, 0, stream>>>(ridx, bitmap, keepf);
  gemm1_kernel<<<NCOMP * MT * NT1, 256, 0, stream>>>(x, ridx, nW1, nb1, eW1, eb1, hbuf);
  gemm2_kernel<<<NCOMP * MT * NT2, 256, 0, stream>>>(hbuf, ridx, nW2, nb2, eW2, eb2, keepf, partial);
  reduce_kernel<<<out_size / 256, 256, 0, stream>>>(partial, out);
}

// Round 3
// 1003.579 us; speedup vs baseline: 1.3794x; 1.2548x over previous
//
#include <hip/hip_runtime.h>
#include <math.h>

// ---------------------------------------------------------------------------
// Disentangler: 32 component-MLPs over sampled token rows + masked seg-pool.
// Round-3 structure: prep passes write PRE-SWIZZLED bf16 buffers (gathered x,
// transposed W1/W2), then both GEMMs run m97-style global_load_lds loops.
// Tiered on ws_size: MODE2 full, MODE1 (A only), MODE0 (reg-staged fp32).
// ---------------------------------------------------------------------------

typedef __attribute__((ext_vector_type(8))) short bf16x8;
typedef __attribute__((ext_vector_type(4))) float f32x4;
typedef unsigned int u32;

constexpr int TT    = 16;
constexpr int TOKN  = 4096;
constexpr int DD    = 2048;
constexpr int HH    = 2048;
constexpr int CC    = 1024;
constexpr int LL    = 1000;
constexpr int NCOMP = 32;
constexpr int MP    = 1024;
constexpr int BM = 128, BN = 128, BK = 64;
constexpr int MT  = MP / BM;
constexpr int NT1 = HH / BN;
constexpr int NT2 = CC / BN;

__device__ __forceinline__ short f2bf(float f) {
  __bf16 h = (__bf16)f;
  return *reinterpret_cast<short*>(&h);
}

// Row swizzle: s(row) = (row&7) ^ ((row>>3)&7).
// Data-granule g (8 bf16 of k=8g..8g+7 within a 64-elem chunk) lives at slot
// g ^ s(row).  Conflict-free (2-way max) for: consecutive-row ds_write,
// stride-4-row ds_write, consecutive-16-row ds_read_b128 (enumerated).
__device__ __forceinline__ int swz(int row) {
  return (row & 7) ^ ((row >> 3) & 7);
}
__device__ __forceinline__ int sw(int row, int gran) {   // short offset in LDS
  return (row << 6) + ((gran ^ swz(row)) << 3);
}

__device__ __forceinline__ void gl_lds16(const void* g, void* l) {
  __builtin_amdgcn_global_load_lds(
      (const __attribute__((address_space(1))) u32*)g,
      (__attribute__((address_space(3))) u32*)l, 16, 0, 0);
}

// --------------------------- dedup ----------------------------------------
__global__ void dedup_kernel(const int* __restrict__ ridx,
                             unsigned* __restrict__ bitmap,
                             float* __restrict__ keepf) {
  int comp = blockIdx.x;
  for (int l = threadIdx.x; l < MP; l += 256) {
    float kv = 0.0f;
    if (l < LL) {
      int r = ridx[comp * LL + l];
      unsigned bit = 1u << (r & 31);
      unsigned old = atomicOr(&bitmap[(comp << 10) + (r >> 5)], bit);
      kv = (old & bit) ? 0.0f : 1.0f;
    }
    keepf[(comp << 10) + l] = kv;
  }
}

// --------------------------- gather: x rows -> pre-swizzled bf16 -----------
__global__ __launch_bounds__(256) void gather_kernel(
    const float* __restrict__ x, const int* __restrict__ ridx,
    short* __restrict__ Ab) {
  int bid = blockIdx.x;
  int comp = bid >> 7, rgrp = bid & 127;
  int t = threadIdx.x;
  int tr = t >> 5, tn = t & 31;
  int m = rgrp * 8 + tr;
  int mi = m < LL ? m : LL - 1;
  int r = ridx[comp * LL + mi];
  int tokoff = comp >= 16 ? TOKN / 2 : 0;
  const float* src = x + ((size_t)(r >> 11) * TOKN + (r & 2047) + tokoff) * DD;
  short* drow = Ab + ((size_t)(comp * MP + m)) * DD;
  int s_m = swz(m & 127);
#pragma unroll
  for (int i = 0; i < 8; ++i) {
    int gi = tn + 32 * i;                    // granule 0..255 of the row
    float4 f0 = *reinterpret_cast<const float4*>(src + gi * 8);
    float4 f1 = *reinterpret_cast<const float4*>(src + gi * 8 + 4);
    bf16x8 pk;
    pk[0]=f2bf(f0.x); pk[1]=f2bf(f0.y); pk[2]=f2bf(f0.z); pk[3]=f2bf(f0.w);
    pk[4]=f2bf(f1.x); pk[5]=f2bf(f1.y); pk[6]=f2bf(f1.z); pk[7]=f2bf(f1.w);
    int c = gi >> 3, g = gi & 7;
    *reinterpret_cast<bf16x8*>(&drow[c * 64 + ((g ^ s_m) << 3)]) = pk;
  }
}

// --------------------------- transpose W -> pre-swizzled bf16 [n][k] -------
__global__ __launch_bounds__(256) void transW_kernel(
    const float* __restrict__ nsrc, const float* __restrict__ esrc,
    short* __restrict__ dst, int N, int NTt) {
  __shared__ float tile[64][65];
  int bid = blockIdx.x;
  int comp = bid / (32 * NTt);
  int rem = bid % (32 * NTt);
  int kt = rem / NTt, ntile = rem % NTt;
  int k0 = kt * 64, n0 = ntile * 64;
  const float* src = (comp < 16) ? nsrc + (size_t)comp * DD * N
                                 : esrc + (size_t)(comp - 16) * DD * N;
  int t = threadIdx.x;
  int kr = t >> 2, j0 = (t & 3) * 16;
  const float* sp = src + (size_t)(k0 + kr) * N + n0 + j0;
#pragma unroll
  for (int e = 0; e < 4; ++e) {
    float4 v = *reinterpret_cast<const float4*>(sp + 4 * e);
    tile[kr][j0 + 4*e]     = v.x;
    tile[kr][j0 + 4*e + 1] = v.y;
    tile[kr][j0 + 4*e + 2] = v.z;
    tile[kr][j0 + 4*e + 3] = v.w;
  }
  __syncthreads();
  int nr = t >> 2, i0 = (t & 3) * 16;
  int n = n0 + nr;
  int s_n = swz(n & 127);
  short* drow = dst + ((size_t)comp * N + n) * DD;   // K == 2048 for W1 and W2
  int chunk = k0 >> 6;
#pragma unroll
  for (int h = 0; h < 2; ++h) {
    int g = ((i0 >> 3) + h) & 7;
    bf16x8 pk;
#pragma unroll
    for (int e = 0; e < 8; ++e) pk[e] = f2bf(tile[i0 + h * 8 + e][nr]);
    *reinterpret_cast<bf16x8*>(&drow[chunk * 64 + ((g ^ s_n) << 3)]) = pk;
  }
}

// --------------------------- GEMM1: h = gelu(x_sel @ W1 + b1) --------------
template<int MODE>
__global__ __launch_bounds__(256, 2) void gemm1_kernel(
    const float* __restrict__ x, const int* __restrict__ ridx,
    const float* __restrict__ nW1, const float* __restrict__ nb1,
    const float* __restrict__ eW1, const float* __restrict__ eb1,
    const short* __restrict__ Ab, const short* __restrict__ Wt1,
    short* __restrict__ hbuf) {
  __shared__ char smem[32768];
  short* As = (short*)smem;
  short* Bs = (short*)(smem + 16384);

  int bid  = blockIdx.x;
  int comp = bid / (MT * NT1);
  int rem  = bid % (MT * NT1);
  int mt = rem / NT1, nt = rem % NT1;
  bool isEdge = comp >= 16;
  int k16 = isEdge ? comp - 16 : comp;
  const float* W1 = (isEdge ? eW1 : nW1) + (size_t)k16 * DD * HH;
  const float* b1 = (isEdge ? eb1 : nb1) + (size_t)k16 * HH;

  int tid = threadIdx.x;
  int lane = tid & 63, wid = tid >> 6;
  int wm = (wid >> 1) << 6, wn = (wid & 1) << 6;
  int lr = lane & 15, lg = lane >> 4;
  int am = tid & 127, akr = tid >> 7;
  int tn = tid & 31, tkb = tid >> 5, bn0 = tn * 4;

  // ---- A setup ----
  const short* aSrcQ[4]; int ldsOffA[4];
  const float* arow = nullptr;
  if constexpr (MODE >= 1) {
#pragma unroll
    for (int q = 0; q < 4; ++q) {
      int gidx = (q * 4 + wid) * 64 + lane;
      int ar = gidx >> 3, aslot = gidx & 7;
      aSrcQ[q] = Ab + ((size_t)(comp * MP + mt * BM + ar)) * DD + aslot * 8;
      ldsOffA[q] = (q * 4 + wid) * 512;           // shorts (1 KiB per instr)
    }
  } else {
    int mglob = mt * BM + am;
    int mi = mglob < LL ? mglob : LL - 1;
    int r = ridx[comp * LL + mi];
    int tokoff = isEdge ? (TOKN / 2) : 0;
    arow = x + ((size_t)(r >> 11) * TOKN + (r & 2047) + tokoff) * DD;
  }
  // ---- B setup ----
  const short* bSrcQ[4]; int ldsOffB[4];
  const float* bptr = nullptr;
  if constexpr (MODE == 2) {
#pragma unroll
    for (int q = 0; q < 4; ++q) {
      int gidx = (q * 4 + wid) * 64 + lane;
      int br = gidx >> 3, bslot = gidx & 7;
      bSrcQ[q] = Wt1 + ((size_t)(comp * HH + nt * BN + br)) * DD + bslot * 8;
      ldsOffB[q] = (q * 4 + wid) * 512;
    }
  } else {
    bptr = W1 + nt * BN + bn0;
  }

  float4 aR[8], bR[8];
  if constexpr (MODE == 0) {
#pragma unroll
    for (int i = 0; i < 8; ++i)
      aR[i] = *reinterpret_cast<const float4*>(arow + akr * 32 + 4 * i);
  }
  if constexpr (MODE <= 1) {
#pragma unroll
    for (int i = 0; i < 8; ++i)
      bR[i] = *reinterpret_cast<const float4*>(bptr + (size_t)(tkb * 8 + i) * HH);
  }

  f32x4 acc[4][4] = {};

  for (int k0 = 0; k0 < DD; k0 += BK) {
    int chunk = k0 >> 6;
    __syncthreads();
    if constexpr (MODE >= 1) {
#pragma unroll
      for (int q = 0; q < 4; ++q)
        gl_lds16(aSrcQ[q] + chunk * 64, As + ldsOffA[q]);
    } else {
#pragma unroll
      for (int g = 0; g < 4; ++g) {
        bf16x8 pk;
#pragma unroll
        for (int e = 0; e < 8; ++e)
          pk[e] = f2bf((&aR[2 * g + (e >> 2)].x)[e & 3]);
        *reinterpret_cast<bf16x8*>(&As[sw(am, akr * 4 + g)]) = pk;
      }
    }
    if constexpr (MODE == 2) {
#pragma unroll
      for (int q = 0; q < 4; ++q)
        gl_lds16(bSrcQ[q] + chunk * 64, Bs + ldsOffB[q]);
    } else {
#pragma unroll
      for (int j = 0; j < 4; ++j) {
        bf16x8 pk;
#pragma unroll
        for (int i = 0; i < 8; ++i) pk[i] = f2bf((&bR[i].x)[j]);
        *reinterpret_cast<bf16x8*>(&Bs[sw(bn0 + j, tkb)]) = pk;
      }
    }
    __syncthreads();

    if (k0 + BK < DD) {
      if constexpr (MODE == 0) {
#pragma unroll
        for (int i = 0; i < 8; ++i)
          aR[i] = *reinterpret_cast<const float4*>(arow + k0 + BK + akr * 32 + 4 * i);
      }
      if constexpr (MODE <= 1) {
#pragma unroll
        for (int i = 0; i < 8; ++i)
          bR[i] = *reinterpret_cast<const float4*>(bptr + (size_t)(k0 + BK + tkb * 8 + i) * HH);
      }
    }

#pragma unroll
    for (int kk = 0; kk < 2; ++kk) {
      bf16x8 af[4], bfr[4];
#pragma unroll
      for (int i = 0; i < 4; ++i)
        af[i] = *reinterpret_cast<const bf16x8*>(&As[sw(wm + i * 16 + lr, kk * 4 + lg)]);
#pragma unroll
      for (int j = 0; j < 4; ++j)
        bfr[j] = *reinterpret_cast<const bf16x8*>(&Bs[sw(wn + j * 16 + lr, kk * 4 + lg)]);
#pragma unroll
      for (int i = 0; i < 4; ++i)
#pragma unroll
        for (int j = 0; j < 4; ++j)
          acc[i][j] = __builtin_amdgcn_mfma_f32_16x16x32_bf16(af[i], bfr[j], acc[i][j], 0, 0, 0);
    }
  }

  // epilogue: +b1, exact gelu, bounce through LDS, coalesced bf16 h-store
  __syncthreads();
  short* Cs = (short*)smem;                       // 128x128 bf16 = 32 KiB
  const float* b1p = b1 + nt * BN;
#pragma unroll
  for (int i = 0; i < 4; ++i)
#pragma unroll
    for (int j = 0; j < 4; ++j) {
      int nl = wn + j * 16 + lr;
      float bias = b1p[nl];
#pragma unroll
      for (int rr = 0; rr < 4; ++rr) {
        int ml = wm + i * 16 + lg * 4 + rr;
        float v = acc[i][j][rr] + bias;
        float ge = 0.5f * v * (1.0f + erff(v * 0.70710678118654752f));
        Cs[ml * 128 + nl] = f2bf(ge);
      }
    }
  __syncthreads();
  short* hblk = hbuf + ((size_t)(comp * MP + mt * BM)) * HH + nt * BN;
#pragma unroll
  for (int q = 0; q < 8; ++q) {
    int gl2 = q * 256 + tid;
    int r = gl2 >> 4, gg = gl2 & 15;             // 4 consecutive rows / wave
    bf16x8 v = *reinterpret_cast<const bf16x8*>(&Cs[r * 128 + gg * 8]);
    *reinterpret_cast<bf16x8*>(&hblk[(size_t)r * HH + gg * 8]) = v;
  }
}

// --------------------------- GEMM2: o = h @ W2 + b2, masked seg-reduce -----
template<int MODE>
__global__ __launch_bounds__(256, 2) void gemm2_kernel(
    const short* __restrict__ hbuf, const int* __restrict__ ridx,
    const float* __restrict__ nW2, const float* __restrict__ nb2,
    const float* __restrict__ eW2, const float* __restrict__ eb2,
    const short* __restrict__ Wt2,
    const float* __restrict__ keepf, float* __restrict__ partial) {
  __shared__ char smem[32768];
  short* As = (short*)smem;
  short* Bs = (short*)(smem + 16384);
  __shared__ float part[TT * BN];
  __shared__ int   tarr[BM];
  __shared__ float karr[BM];

  int bid  = blockIdx.x;
  int comp = bid / (MT * NT2);
  int rem  = bid % (MT * NT2);
  int mt = rem / NT2, nt = rem % NT2;
  bool isEdge = comp >= 16;
  int k16 = isEdge ? comp - 16 : comp;
  const float* W2 = (isEdge ? eW2 : nW2) + (size_t)k16 * HH * CC;
  const float* b2 = (isEdge ? eb2 : nb2) + (size_t)k16 * CC;

  int tid = threadIdx.x;
  int am = tid & 127, akr = tid >> 7;
  int lane = tid & 63, wid = tid >> 6;
  int wm = (wid >> 1) << 6, wn = (wid & 1) << 6;
  int lr = lane & 15, lg = lane >> 4;
  int tn = tid & 31, tkb = tid >> 5, bn0 = tn * 4;

  if (tid < BM) {
    int mglob = mt * BM + tid;
    int mi = mglob < LL ? mglob : LL - 1;
    int r2 = ridx[comp * LL + mi];
    tarr[tid] = r2 >> 11;
    karr[tid] = keepf[(comp << 10) + mglob];
  }
  for (int e = tid; e < TT * BN; e += 256) part[e] = 0.0f;

  const short* harow = hbuf + ((size_t)(comp * MP + mt * BM + am)) * HH + akr * 32;

  const short* bSrcQ[4]; int ldsOffB[4];
  const float* bptr = nullptr;
  if constexpr (MODE == 2) {
#pragma unroll
    for (int q = 0; q < 4; ++q) {
      int gidx = (q * 4 + wid) * 64 + lane;
      int br = gidx >> 3, bslot = gidx & 7;
      bSrcQ[q] = Wt2 + ((size_t)(comp * CC + nt * BN + br)) * HH + bslot * 8;
      ldsOffB[q] = (q * 4 + wid) * 512;
    }
  } else {
    bptr = W2 + nt * BN + bn0;
  }

  bf16x8 aR[4]; float4 bR[8];
#pragma unroll
  for (int g = 0; g < 4; ++g)
    aR[g] = *reinterpret_cast<const bf16x8*>(&harow[g * 8]);
  if constexpr (MODE < 2) {
#pragma unroll
    for (int i = 0; i < 8; ++i)
      bR[i] = *reinterpret_cast<const float4*>(bptr + (size_t)(tkb * 8 + i) * CC);
  }

  f32x4 acc[4][4] = {};

  for (int k0 = 0; k0 < HH; k0 += BK) {
    __syncthreads();
#pragma unroll
    for (int g = 0; g < 4; ++g)
      *reinterpret_cast<bf16x8*>(&As[sw(am, akr * 4 + g)]) = aR[g];
    if constexpr (MODE == 2) {
#pragma unroll
      for (int q = 0; q < 4; ++q)
        gl_lds16(bSrcQ[q] + (k0 >> 6) * 64, Bs + ldsOffB[q]);
    } else {
#pragma unroll
      for (int j = 0; j < 4; ++j) {
        bf16x8 pk;
#pragma unroll
        for (int i = 0; i < 8; ++i) pk[i] = f2bf((&bR[i].x)[j]);
        *reinterpret_cast<bf16x8*>(&Bs[sw(bn0 + j, tkb)]) = pk;
      }
    }
    __syncthreads();

    if (k0 + BK < HH) {
#pragma unroll
      for (int g = 0; g < 4; ++g)
        aR[g] = *reinterpret_cast<const bf16x8*>(&harow[k0 + BK + g * 8]);
      if constexpr (MODE < 2) {
#pragma unroll
        for (int i = 0; i < 8; ++i)
          bR[i] = *reinterpret_cast<const float4*>(bptr + (size_t)(k0 + BK + tkb * 8 + i) * CC);
      }
    }

#pragma unroll
    for (int kk = 0; kk < 2; ++kk) {
      bf16x8 af[4], bfr[4];
#pragma unroll
      for (int i = 0; i < 4; ++i)
        af[i] = *reinterpret_cast<const bf16x8*>(&As[sw(wm + i * 16 + lr, kk * 4 + lg)]);
#pragma unroll
      for (int j = 0; j < 4; ++j)
        bfr[j] = *reinterpret_cast<const bf16x8*>(&Bs[sw(wn + j * 16 + lr, kk * 4 + lg)]);
#pragma unroll
      for (int i = 0; i < 4; ++i)
#pragma unroll
        for (int j = 0; j < 4; ++j)
          acc[i][j] = __builtin_amdgcn_mfma_f32_16x16x32_bf16(af[i], bfr[j], acc[i][j], 0, 0, 0);
    }
  }

  const float* b2p = b2 + nt * BN;
#pragma unroll
  for (int i = 0; i < 4; ++i)
#pragma unroll
    for (int j = 0; j < 4; ++j) {
      int nl = wn + j * 16 + lr;
      float bias = b2p[nl];
#pragma unroll
      for (int rr = 0; rr < 4; ++rr) {
        int ml = wm + i * 16 + lg * 4 + rr;
        float v = (acc[i][j][rr] + bias) * karr[ml];
        atomicAdd(&part[tarr[ml] * BN + nl], v);
      }
    }
  __syncthreads();
  float* pout = partial + ((size_t)(comp * MT + mt)) * TT * CC + nt * BN;
  for (int e = tid; e < TT * BN; e += 256) {
    int t2 = e >> 7, c = e & 127;
    pout[(size_t)t2 * CC + c] = part[e];
  }
}

// --------------------------- final reduce over m-tiles ---------------------
__global__ void reduce_kernel(const float* __restrict__ partial,
                              float* __restrict__ out) {
  int idx = blockIdx.x * 256 + threadIdx.x;
  int c    = idx & (CC - 1);
  int comp = (idx >> 10) & (NCOMP - 1);
  int t    = idx >> 15;
  float s = 0.0f;
#pragma unroll
  for (int mt = 0; mt < MT; ++mt)
    s += partial[(((size_t)(comp * MT + mt)) * TT + t) * CC + c];
  out[idx] = s * (1.0f / 4096.0f);
}

// ---------------------------------------------------------------------------
extern "C" void kernel_launch(void* const* d_in, const int* in_sizes, int n_in,
                              void* d_out, int out_size, void* d_ws, size_t ws_size,
                              hipStream_t stream) {
  const float* x    = (const float*)d_in[0];
  const int*   ridx = (const int*)d_in[3];
  const float* nW1  = (const float*)d_in[4];
  const float* nb1  = (const float*)d_in[5];
  const float* nW2  = (const float*)d_in[6];
  const float* nb2  = (const float*)d_in[7];
  const float* eW1  = (const float*)d_in[8];
  const float* eb1  = (const float*)d_in[9];
  const float* eW2  = (const float*)d_in[10];
  const float* eb2  = (const float*)d_in[11];
  float* out = (float*)d_out;

  // ws layout:
  //  [h bf16 134MB][bitmap 128KB][keep 128KB][partial 16MB]   (base, MODE0)
  //  [Ab / Wt2 bf16 134MB]                                    (MODE>=1)
  //  [Wt1 bf16 268MB]                                         (MODE2)
  const size_t H_B   = (size_t)NCOMP * MP * HH * 2;
  const size_t BMP_B = (size_t)NCOMP * 1024 * 4;
  const size_t KP_B  = (size_t)NCOMP * 1024 * 4;
  const size_t PRT_B = (size_t)NCOMP * MT * TT * CC * 4;
  const size_t AB_B  = (size_t)NCOMP * MP * DD * 2;   // == Wt2 size
  const size_t WT1_B = (size_t)NCOMP * HH * DD * 2;
  const size_t need0 = H_B + BMP_B + KP_B + PRT_B;
  const size_t need1 = need0 + AB_B;
  const size_t need2 = need1 + WT1_B;

  char* ws = (char*)d_ws;
  short* hbuf      = (short*)ws;
  unsigned* bitmap = (unsigned*)(ws + H_B);
  float* keepf     = (float*)(ws + H_B + BMP_B);
  float* partial   = (float*)(ws + H_B + BMP_B + KP_B);
  short* Ab        = (short*)(ws + need0);            // also Wt2 after gemm1
  short* Wt1       = (short*)(ws + need1);

  int mode = (ws_size >= need2) ? 2 : (ws_size >= need1) ? 1 : 0;

  hipMemsetAsync(bitmap, 0, BMP_B, stream);
  dedup_kernel<<<NCOMP, 256, 0, stream>>>(ridx, bitmap, keepf);

  if (mode >= 1)
    gather_kernel<<<NCOMP * 128, 256, 0, stream>>>(x, ridx, Ab);
  if (mode == 2)
    transW_kernel<<<NCOMP * 32 * 32, 256, 0, stream>>>(nW1, eW1, Wt1, HH, 32);

  if (mode == 2)
    gemm1_kernel<2><<<NCOMP * MT * NT1, 256, 0, stream>>>(x, ridx, nW1, nb1, eW1, eb1, Ab, Wt1, hbuf);
  else if (mode == 1)
    gemm1_kernel<1><<<NCOMP * MT * NT1, 256, 0, stream>>>(x, ridx, nW1, nb1, eW1, eb1, Ab, Wt1, hbuf);
  else
    gemm1_kernel<0><<<NCOMP * MT * NT1, 256, 0, stream>>>(x, ridx, nW1, nb1, eW1, eb1, Ab, Wt1, hbuf);

  if (mode == 2) {
    // Wt2 reuses the (now dead) Ab region
    transW_kernel<<<NCOMP * 32 * 16, 256, 0, stream>>>(nW2, eW2, Ab, CC, 16);
    gemm2_kernel<2><<<NCOMP * MT * NT2, 256, 0, stream>>>(hbuf, ridx, nW2, nb2, eW2, eb2, Ab, keepf, partial);
  } else {
    gemm2_kernel<0><<<NCOMP * MT * NT2, 256, 0, stream>>>(hbuf, ridx, nW2, nb2, eW2, eb2, Ab, keepf, partial);
  }

  reduce_kernel<<<out_size / 256, 256, 0, stream>>>(partial, out);
}

// Round 4
// 972.199 us; speedup vs baseline: 1.4239x; 1.0323x over previous
//
#include <hip/hip_runtime.h>
#include <math.h>

// ---------------------------------------------------------------------------
// Disentangler: 32 component-MLPs over sampled token rows + masked seg-pool.
// Round-4: both GEMMs are pure global_load_lds loops over PRE-SWIZZLED bf16
// buffers (Ab from gather, Wt1/Wt2 from transW, h written swizzled by gemm1),
// single-barrier double-buffered K-loop, XCD-chunked block swizzle (T1).
// ---------------------------------------------------------------------------

typedef __attribute__((ext_vector_type(8))) short bf16x8;
typedef __attribute__((ext_vector_type(4))) short s16x4;
typedef __attribute__((ext_vector_type(4))) float f32x4;
typedef unsigned int u32;

constexpr int TT    = 16;
constexpr int TOKN  = 4096;
constexpr int DD    = 2048;
constexpr int HH    = 2048;
constexpr int CC    = 1024;
constexpr int LL    = 1000;
constexpr int NCOMP = 32;
constexpr int MP    = 1024;
constexpr int BM = 128, BN = 128, BK = 64;
constexpr int MT  = MP / BM;
constexpr int NT1 = HH / BN;
constexpr int NT2 = CC / BN;

__device__ __forceinline__ short f2bf(float f) {
  __bf16 h = (__bf16)f;
  return *reinterpret_cast<short*>(&h);
}
// Row swizzle (function of row mod 64): granule g of a 64-elem chunk lives at
// slot g ^ swz(row). Same layout in Ab, Wt1, Wt2, and h.
__device__ __forceinline__ int swz(int row) {
  return (row & 7) ^ ((row >> 3) & 7);
}
__device__ __forceinline__ int sw(int row, int gran) {   // short offset in LDS
  return (row << 6) + ((gran ^ swz(row)) << 3);
}
__device__ __forceinline__ void gl_lds16(const void* g, void* l) {
  __builtin_amdgcn_global_load_lds(
      (const __attribute__((address_space(1))) u32*)g,
      (__attribute__((address_space(3))) u32*)l, 16, 0, 0);
}

// --------------------------- dedup ----------------------------------------
__global__ void dedup_kernel(const int* __restrict__ ridx,
                             unsigned* __restrict__ bitmap,
                             float* __restrict__ keepf) {
  int comp = blockIdx.x;
  for (int l = threadIdx.x; l < MP; l += 256) {
    float kv = 0.0f;
    if (l < LL) {
      int r = ridx[comp * LL + l];
      unsigned bit = 1u << (r & 31);
      unsigned old = atomicOr(&bitmap[(comp << 10) + (r >> 5)], bit);
      kv = (old & bit) ? 0.0f : 1.0f;
    }
    keepf[(comp << 10) + l] = kv;
  }
}

// --------------------------- gather: x rows -> pre-swizzled bf16 -----------
__global__ __launch_bounds__(256) void gather_kernel(
    const float* __restrict__ x, const int* __restrict__ ridx,
    short* __restrict__ Ab) {
  int bid = blockIdx.x;
  int comp = bid >> 7, rgrp = bid & 127;
  int t = threadIdx.x;
  int tr = t >> 5, tn = t & 31;
  int m = rgrp * 8 + tr;
  int mi = m < LL ? m : LL - 1;
  int r = ridx[comp * LL + mi];
  int tokoff = comp >= 16 ? TOKN / 2 : 0;
  const float* src = x + ((size_t)(r >> 11) * TOKN + (r & 2047) + tokoff) * DD;
  short* drow = Ab + ((size_t)(comp * MP + m)) * DD;
  int s_m = swz(m);
#pragma unroll
  for (int i = 0; i < 8; ++i) {
    int gi = tn + 32 * i;
    float4 f0 = *reinterpret_cast<const float4*>(src + gi * 8);
    float4 f1 = *reinterpret_cast<const float4*>(src + gi * 8 + 4);
    bf16x8 pk;
    pk[0]=f2bf(f0.x); pk[1]=f2bf(f0.y); pk[2]=f2bf(f0.z); pk[3]=f2bf(f0.w);
    pk[4]=f2bf(f1.x); pk[5]=f2bf(f1.y); pk[6]=f2bf(f1.z); pk[7]=f2bf(f1.w);
    int c = gi >> 3, g = gi & 7;
    *reinterpret_cast<bf16x8*>(&drow[c * 64 + ((g ^ s_m) << 3)]) = pk;
  }
}

// --------------------------- transpose W -> pre-swizzled bf16 [n][k] -------
__global__ __launch_bounds__(256) void transW_kernel(
    const float* __restrict__ nsrc, const float* __restrict__ esrc,
    short* __restrict__ dst, int N, int NTt) {
  __shared__ float tile[64][65];
  int bid = blockIdx.x;
  int comp = bid / (32 * NTt);
  int rem = bid % (32 * NTt);
  int kt = rem / NTt, ntile = rem % NTt;
  int k0 = kt * 64, n0 = ntile * 64;
  const float* src = (comp < 16) ? nsrc + (size_t)comp * DD * N
                                 : esrc + (size_t)(comp - 16) * DD * N;
  int t = threadIdx.x;
  int kr = t >> 2, j0 = (t & 3) * 16;
  const float* sp = src + (size_t)(k0 + kr) * N + n0 + j0;
#pragma unroll
  for (int e = 0; e < 4; ++e) {
    float4 v = *reinterpret_cast<const float4*>(sp + 4 * e);
    tile[kr][j0 + 4*e]     = v.x;
    tile[kr][j0 + 4*e + 1] = v.y;
    tile[kr][j0 + 4*e + 2] = v.z;
    tile[kr][j0 + 4*e + 3] = v.w;
  }
  __syncthreads();
  int nr = t >> 2, i0 = (t & 3) * 16;
  int n = n0 + nr;
  int s_n = swz(n);
  short* drow = dst + ((size_t)comp * N + n) * DD;   // K == 2048 for W1 and W2
  int chunk = k0 >> 6;
#pragma unroll
  for (int h = 0; h < 2; ++h) {
    int g = ((i0 >> 3) + h) & 7;
    bf16x8 pk;
#pragma unroll
    for (int e = 0; e < 8; ++e) pk[e] = f2bf(tile[i0 + h * 8 + e][nr]);
    *reinterpret_cast<bf16x8*>(&drow[chunk * 64 + ((g ^ s_n) << 3)]) = pk;
  }
}

// --------------------------- GEMM1: h = gelu(x_sel @ W1 + b1) --------------
__global__ __launch_bounds__(256, 2) void gemm1_kernel(
    const float* __restrict__ nb1, const float* __restrict__ eb1,
    const short* __restrict__ Ab, const short* __restrict__ Wt1,
    short* __restrict__ hbuf) {
  __shared__ short smem[32768];   // 64 KB: A0|A1|B0|B1, 8192 shorts each

  constexpr int NWG = NCOMP * MT * NT1;   // 4096
  constexpr int CPX = NWG / 8;
  int b0 = blockIdx.x;
  int lb = (b0 & 7) * CPX + (b0 >> 3);    // XCD-chunked (T1), bijective
  int comp = lb / (MT * NT1);
  int rem  = lb % (MT * NT1);
  int mt = rem / NT1, nt = rem % NT1;
  const float* b1 = (comp < 16) ? nb1 + (size_t)comp * HH
                                : eb1 + (size_t)(comp - 16) * HH;

  int tid = threadIdx.x, lane = tid & 63, wid = tid >> 6;
  int wm = (wid >> 1) << 6, wn = (wid & 1) << 6;
  int lr = lane & 15, lg = lane >> 4;

  const short* aSrc[4]; const short* bSrc[4]; int ldsOff[4];
#pragma unroll
  for (int q = 0; q < 4; ++q) {
    int gidx = (q * 4 + wid) * 64 + lane, ar = gidx >> 3, sl = gidx & 7;
    aSrc[q] = Ab  + ((size_t)(comp * MP + mt * BM + ar)) * DD + sl * 8;
    bSrc[q] = Wt1 + ((size_t)(comp * HH + nt * BN + ar)) * DD + sl * 8;
    ldsOff[q] = (q * 4 + wid) * 512;
  }

  f32x4 acc[4][4] = {};
#pragma unroll
  for (int q = 0; q < 4; ++q) gl_lds16(aSrc[q], smem + ldsOff[q]);
#pragma unroll
  for (int q = 0; q < 4; ++q) gl_lds16(bSrc[q], smem + 16384 + ldsOff[q]);

  int cur = 0;
  for (int t = 0; t < DD / BK; ++t) {
    __syncthreads();                       // drains in-flight stage for tile t
    if (t + 1 < DD / BK) {                 // stage t+1: full compute of cover
      int nb = (cur ^ 1) * 8192, off = (t + 1) * 64;
#pragma unroll
      for (int q = 0; q < 4; ++q) gl_lds16(aSrc[q] + off, smem + nb + ldsOff[q]);
#pragma unroll
      for (int q = 0; q < 4; ++q) gl_lds16(bSrc[q] + off, smem + 16384 + nb + ldsOff[q]);
    }
    const short* A = smem + cur * 8192;
    const short* B = smem + 16384 + cur * 8192;
    __builtin_amdgcn_s_setprio(1);
#pragma unroll
    for (int kk = 0; kk < 2; ++kk) {
      bf16x8 af[4], bf_[4];
#pragma unroll
      for (int i = 0; i < 4; ++i)
        af[i] = *reinterpret_cast<const bf16x8*>(&A[sw(wm + i * 16 + lr, kk * 4 + lg)]);
#pragma unroll
      for (int j = 0; j < 4; ++j)
        bf_[j] = *reinterpret_cast<const bf16x8*>(&B[sw(wn + j * 16 + lr, kk * 4 + lg)]);
#pragma unroll
      for (int i = 0; i < 4; ++i)
#pragma unroll
        for (int j = 0; j < 4; ++j)
          acc[i][j] = __builtin_amdgcn_mfma_f32_16x16x32_bf16(af[i], bf_[j], acc[i][j], 0, 0, 0);
    }
    __builtin_amdgcn_s_setprio(0);
    cur ^= 1;
  }

  // epilogue: +b1, exact gelu -> Cs (stride 132: conflict-free b16 writes),
  // then coalesced PRE-SWIZZLED bf16 h store (so gemm2 can global_load_lds it)
  __syncthreads();
  short* Cs = smem;                        // 128*132 = 16896 shorts
  const float* b1p = b1 + nt * BN;
#pragma unroll
  for (int i = 0; i < 4; ++i)
#pragma unroll
    for (int j = 0; j < 4; ++j) {
      int nl = wn + j * 16 + lr;
      float bias = b1p[nl];
#pragma unroll
      for (int rr = 0; rr < 4; ++rr) {
        int ml = wm + i * 16 + lg * 4 + rr;
        float v = acc[i][j][rr] + bias;
        float ge = 0.5f * v * (1.0f + erff(v * 0.70710678118654752f));
        Cs[ml * 132 + nl] = f2bf(ge);
      }
    }
  __syncthreads();
  short* hrow = hbuf + ((size_t)(comp * MP + mt * BM)) * HH;
#pragma unroll
  for (int q = 0; q < 16; ++q) {
    int gl = q * 256 + tid;
    int r = gl >> 5, gg = gl & 31;         // 32 4-short granules per row
    s16x4 v = *reinterpret_cast<const s16x4*>(&Cs[r * 132 + gg * 4]);
    int dst = (nt * 2 + (gg >> 4)) * 64 + ((((gg >> 1) & 7) ^ swz(r)) << 3) + (gg & 1) * 4;
    *reinterpret_cast<s16x4*>(&hrow[(size_t)r * HH + dst]) = v;
  }
}

// --------------------------- GEMM2: o = h @ W2 + b2, masked seg-reduce -----
__global__ __launch_bounds__(256, 2) void gemm2_kernel(
    const short* __restrict__ hbuf, const int* __restrict__ ridx,
    const float* __restrict__ nb2, const float* __restrict__ eb2,
    const short* __restrict__ Wt2,
    const float* __restrict__ keepf, float* __restrict__ partial) {
  __shared__ short smem[32768];

  constexpr int NWG = NCOMP * MT * NT2;   // 2048
  constexpr int CPX = NWG / 8;
  int b0 = blockIdx.x;
  int lb = (b0 & 7) * CPX + (b0 >> 3);
  int comp = lb / (MT * NT2);
  int rem  = lb % (MT * NT2);
  int mt = rem / NT2, nt = rem % NT2;
  const float* b2 = (comp < 16) ? nb2 + (size_t)comp * CC
                                : eb2 + (size_t)(comp - 16) * CC;

  int tid = threadIdx.x, lane = tid & 63, wid = tid >> 6;
  int wm = (wid >> 1) << 6, wn = (wid & 1) << 6;
  int lr = lane & 15, lg = lane >> 4;

  const short* aSrc[4]; const short* bSrc[4]; int ldsOff[4];
#pragma unroll
  for (int q = 0; q < 4; ++q) {
    int gidx = (q * 4 + wid) * 64 + lane, ar = gidx >> 3, sl = gidx & 7;
    aSrc[q] = hbuf + ((size_t)(comp * MP + mt * BM + ar)) * HH + sl * 8;
    bSrc[q] = Wt2  + ((size_t)(comp * CC + nt * BN + ar)) * HH + sl * 8;
    ldsOff[q] = (q * 4 + wid) * 512;
  }

  f32x4 acc[4][4] = {};
#pragma unroll
  for (int q = 0; q < 4; ++q) gl_lds16(aSrc[q], smem + ldsOff[q]);
#pragma unroll
  for (int q = 0; q < 4; ++q) gl_lds16(bSrc[q], smem + 16384 + ldsOff[q]);

  int cur = 0;
  for (int t = 0; t < HH / BK; ++t) {
    __syncthreads();
    if (t + 1 < HH / BK) {
      int nb = (cur ^ 1) * 8192, off = (t + 1) * 64;
#pragma unroll
      for (int q = 0; q < 4; ++q) gl_lds16(aSrc[q] + off, smem + nb + ldsOff[q]);
#pragma unroll
      for (int q = 0; q < 4; ++q) gl_lds16(bSrc[q] + off, smem + 16384 + nb + ldsOff[q]);
    }
    const short* A = smem + cur * 8192;
    const short* B = smem + 16384 + cur * 8192;
    __builtin_amdgcn_s_setprio(1);
#pragma unroll
    for (int kk = 0; kk < 2; ++kk) {
      bf16x8 af[4], bf_[4];
#pragma unroll
      for (int i = 0; i < 4; ++i)
        af[i] = *reinterpret_cast<const bf16x8*>(&A[sw(wm + i * 16 + lr, kk * 4 + lg)]);
#pragma unroll
      for (int j = 0; j < 4; ++j)
        bf_[j] = *reinterpret_cast<const bf16x8*>(&B[sw(wn + j * 16 + lr, kk * 4 + lg)]);
#pragma unroll
      for (int i = 0; i < 4; ++i)
#pragma unroll
        for (int j = 0; j < 4; ++j)
          acc[i][j] = __builtin_amdgcn_mfma_f32_16x16x32_bf16(af[i], bf_[j], acc[i][j], 0, 0, 0);
    }
    __builtin_amdgcn_s_setprio(0);
    cur ^= 1;
  }

  // epilogue: (+b2) * keep, seg-reduce by timestamp (LDS reused for part[])
  __syncthreads();
  float* part = (float*)smem;              // 2048 floats (8 KB)
  int*   tarr = (int*)(smem + 4096);       // byte 8192, 128 ints
  float* karr = (float*)(smem + 4352);     // byte 8704, 128 floats
  if (tid < BM) {
    int mglob = mt * BM + tid;
    int mi = mglob < LL ? mglob : LL - 1;
    int r2 = ridx[comp * LL + mi];
    tarr[tid] = r2 >> 11;
    karr[tid] = keepf[(comp << 10) + mglob];
  }
  for (int e = tid; e < TT * BN; e += 256) part[e] = 0.0f;
  __syncthreads();
  const float* b2p = b2 + nt * BN;
#pragma unroll
  for (int i = 0; i < 4; ++i)
#pragma unroll
    for (int j = 0; j < 4; ++j) {
      int nl = wn + j * 16 + lr;
      float bias = b2p[nl];
#pragma unroll
      for (int rr = 0; rr < 4; ++rr) {
        int ml = wm + i * 16 + lg * 4 + rr;
        float v = (acc[i][j][rr] + bias) * karr[ml];
        atomicAdd(&part[tarr[ml] * BN + nl], v);
      }
    }
  __syncthreads();
  float* pout = partial + ((size_t)(comp * MT + mt)) * TT * CC + nt * BN;
  for (int e = tid; e < TT * BN; e += 256) {
    int t2 = e >> 7, c = e & 127;
    pout[(size_t)t2 * CC + c] = part[e];
  }
}

// --------------------------- final reduce over m-tiles ---------------------
__global__ void reduce_kernel(const float* __restrict__ partial,
                              float* __restrict__ out) {
  int idx = blockIdx.x * 256 + threadIdx.x;
  int c    = idx & (CC - 1);
  int comp = (idx >> 10) & (NCOMP - 1);
  int t    = idx >> 15;
  float s = 0.0f;
#pragma unroll
  for (int mt = 0; mt < MT; ++mt)
    s += partial[(((size_t)(comp * MT + mt)) * TT + t) * CC + c];
  out[idx] = s * (1.0f / 4096.0f);
}

// ---------------------------------------------------------------------------
extern "C" void kernel_launch(void* const* d_in, const int* in_sizes, int n_in,
                              void* d_out, int out_size, void* d_ws, size_t ws_size,
                              hipStream_t stream) {
  const float* x    = (const float*)d_in[0];
  const int*   ridx = (const int*)d_in[3];
  const float* nW1  = (const float*)d_in[4];
  const float* nb1  = (const float*)d_in[5];
  const float* nW2  = (const float*)d_in[6];
  const float* nb2  = (const float*)d_in[7];
  const float* eW1  = (const float*)d_in[8];
  const float* eb1  = (const float*)d_in[9];
  const float* eW2  = (const float*)d_in[10];
  const float* eb2  = (const float*)d_in[11];
  float* out = (float*)d_out;

  // ws: [h 134MB][bitmap][keep][partial 16MB][Ab/Wt2 134MB][Wt1 268MB] ~554MB
  const size_t H_B   = (size_t)NCOMP * MP * HH * 2;
  const size_t BMP_B = (size_t)NCOMP * 1024 * 4;
  const size_t KP_B  = (size_t)NCOMP * 1024 * 4;
  const size_t PRT_B = (size_t)NCOMP * MT * TT * CC * 4;
  const size_t base  = H_B + BMP_B + KP_B + PRT_B;
  const size_t AB_B  = (size_t)NCOMP * MP * DD * 2;

  char* ws = (char*)d_ws;
  short* hbuf      = (short*)ws;
  unsigned* bitmap = (unsigned*)(ws + H_B);
  float* keepf     = (float*)(ws + H_B + BMP_B);
  float* partial   = (float*)(ws + H_B + BMP_B + KP_B);
  short* Ab        = (short*)(ws + base);            // reused as Wt2 later
  short* Wt1       = (short*)(ws + base + AB_B);

  hipMemsetAsync(bitmap, 0, BMP_B, stream);
  dedup_kernel<<<NCOMP, 256, 0, stream>>>(ridx, bitmap, keepf);
  gather_kernel<<<NCOMP * 128, 256, 0, stream>>>(x, ridx, Ab);
  transW_kernel<<<NCOMP * 32 * 32, 256, 0, stream>>>(nW1, eW1, Wt1, HH, 32);
  gemm1_kernel<<<NCOMP * MT * NT1, 256, 0, stream>>>(nb1, eb1, Ab, Wt1, hbuf);
  transW_kernel<<<NCOMP * 32 * 16, 256, 0, stream>>>(nW2, eW2, Ab, CC, 16);
  gemm2_kernel<<<NCOMP * MT * NT2, 256, 0, stream>>>(hbuf, ridx, nb2, eb2, Ab, keepf, partial);
  reduce_kernel<<<out_size / 256, 256, 0, stream>>>(partial, out);
}

// Round 5
// 946.766 us; speedup vs baseline: 1.4622x; 1.0269x over previous
//
#include <hip/hip_runtime.h>
#include <math.h>

// ---------------------------------------------------------------------------
// Disentangler: 32 component-MLPs over sampled token rows + masked seg-pool.
// Round-5: counted-vmcnt pipeline (T4) — raw s_barrier + s_waitcnt vmcnt(8),
// depth-2 stage issue across barriers, 2 LDS buffers. Operands pre-swizzled
// bf16 (Ab, Wt1, Wt2, h), pure global_load_lds staging, T1 XCD swizzle.
// ---------------------------------------------------------------------------

typedef __attribute__((ext_vector_type(8))) short bf16x8;
typedef __attribute__((ext_vector_type(4))) short s16x4;
typedef __attribute__((ext_vector_type(4))) float f32x4;
typedef unsigned int u32;

constexpr int TT    = 16;
constexpr int TOKN  = 4096;
constexpr int DD    = 2048;
constexpr int HH    = 2048;
constexpr int CC    = 1024;
constexpr int LL    = 1000;
constexpr int NCOMP = 32;
constexpr int MP    = 1024;
constexpr int BM = 128, BN = 128, BK = 64;
constexpr int MT  = MP / BM;
constexpr int NT1 = HH / BN;
constexpr int NT2 = CC / BN;

__device__ __forceinline__ short f2bf(float f) {
  __bf16 h = (__bf16)f;
  return *reinterpret_cast<short*>(&h);
}
// Row swizzle (function of row mod 64): granule g of a 64-elem chunk lives at
// slot g ^ swz(row). Same layout in Ab, Wt1, Wt2, and h.
__device__ __forceinline__ int swz(int row) {
  return (row & 7) ^ ((row >> 3) & 7);
}
__device__ __forceinline__ int sw(int row, int gran) {   // short offset in LDS
  return (row << 6) + ((gran ^ swz(row)) << 3);
}
__device__ __forceinline__ void gl_lds16(const void* g, void* l) {
  __builtin_amdgcn_global_load_lds(
      (const __attribute__((address_space(1))) u32*)g,
      (__attribute__((address_space(3))) u32*)l, 16, 0, 0);
}

// --------------------------- dedup ----------------------------------------
__global__ void dedup_kernel(const int* __restrict__ ridx,
                             unsigned* __restrict__ bitmap,
                             float* __restrict__ keepf) {
  int comp = blockIdx.x;
  for (int l = threadIdx.x; l < MP; l += 256) {
    float kv = 0.0f;
    if (l < LL) {
      int r = ridx[comp * LL + l];
      unsigned bit = 1u << (r & 31);
      unsigned old = atomicOr(&bitmap[(comp << 10) + (r >> 5)], bit);
      kv = (old & bit) ? 0.0f : 1.0f;
    }
    keepf[(comp << 10) + l] = kv;
  }
}

// --------------------------- gather: x rows -> pre-swizzled bf16 -----------
__global__ __launch_bounds__(256) void gather_kernel(
    const float* __restrict__ x, const int* __restrict__ ridx,
    short* __restrict__ Ab) {
  int bid = blockIdx.x;
  int comp = bid >> 7, rgrp = bid & 127;
  int t = threadIdx.x;
  int tr = t >> 5, tn = t & 31;
  int m = rgrp * 8 + tr;
  int mi = m < LL ? m : LL - 1;
  int r = ridx[comp * LL + mi];
  int tokoff = comp >= 16 ? TOKN / 2 : 0;
  const float* src = x + ((size_t)(r >> 11) * TOKN + (r & 2047) + tokoff) * DD;
  short* drow = Ab + ((size_t)(comp * MP + m)) * DD;
  int s_m = swz(m);
#pragma unroll
  for (int i = 0; i < 8; ++i) {
    int gi = tn + 32 * i;
    float4 f0 = *reinterpret_cast<const float4*>(src + gi * 8);
    float4 f1 = *reinterpret_cast<const float4*>(src + gi * 8 + 4);
    bf16x8 pk;
    pk[0]=f2bf(f0.x); pk[1]=f2bf(f0.y); pk[2]=f2bf(f0.z); pk[3]=f2bf(f0.w);
    pk[4]=f2bf(f1.x); pk[5]=f2bf(f1.y); pk[6]=f2bf(f1.z); pk[7]=f2bf(f1.w);
    int c = gi >> 3, g = gi & 7;
    *reinterpret_cast<bf16x8*>(&drow[c * 64 + ((g ^ s_m) << 3)]) = pk;
  }
}

// --------------------------- transpose W -> pre-swizzled bf16 [n][k] -------
__global__ __launch_bounds__(256) void transW_kernel(
    const float* __restrict__ nsrc, const float* __restrict__ esrc,
    short* __restrict__ dst, int N, int NTt) {
  __shared__ float tile[64][65];
  int bid = blockIdx.x;
  int comp = bid / (32 * NTt);
  int rem = bid % (32 * NTt);
  int kt = rem / NTt, ntile = rem % NTt;
  int k0 = kt * 64, n0 = ntile * 64;
  const float* src = (comp < 16) ? nsrc + (size_t)comp * DD * N
                                 : esrc + (size_t)(comp - 16) * DD * N;
  int t = threadIdx.x;
  int kr = t >> 2, j0 = (t & 3) * 16;
  const float* sp = src + (size_t)(k0 + kr) * N + n0 + j0;
#pragma unroll
  for (int e = 0; e < 4; ++e) {
    float4 v = *reinterpret_cast<const float4*>(sp + 4 * e);
    tile[kr][j0 + 4*e]     = v.x;
    tile[kr][j0 + 4*e + 1] = v.y;
    tile[kr][j0 + 4*e + 2] = v.z;
    tile[kr][j0 + 4*e + 3] = v.w;
  }
  __syncthreads();
  int nr = t >> 2, i0 = (t & 3) * 16;
  int n = n0 + nr;
  int s_n = swz(n);
  short* drow = dst + ((size_t)comp * N + n) * DD;   // K == 2048 for W1 and W2
  int chunk = k0 >> 6;
#pragma unroll
  for (int h = 0; h < 2; ++h) {
    int g = ((i0 >> 3) + h) & 7;
    bf16x8 pk;
#pragma unroll
    for (int e = 0; e < 8; ++e) pk[e] = f2bf(tile[i0 + h * 8 + e][nr]);
    *reinterpret_cast<bf16x8*>(&drow[chunk * 64 + ((g ^ s_n) << 3)]) = pk;
  }
}

// --------------------------- GEMM1: h = gelu(x_sel @ W1 + b1) --------------
__global__ __launch_bounds__(256, 2) void gemm1_kernel(
    const float* __restrict__ nb1, const float* __restrict__ eb1,
    const short* __restrict__ Ab, const short* __restrict__ Wt1,
    short* __restrict__ hbuf) {
  __shared__ short smem[32768];   // 64 KB: A0|A1|B0|B1, 8192 shorts each

  constexpr int NWG = NCOMP * MT * NT1;   // 4096
  constexpr int CPX = NWG / 8;
  int b0 = blockIdx.x;
  int lb = (b0 & 7) * CPX + (b0 >> 3);    // XCD-chunked (T1), bijective
  int comp = lb / (MT * NT1);
  int rem  = lb % (MT * NT1);
  int mt = rem / NT1, nt = rem % NT1;
  const float* b1 = (comp < 16) ? nb1 + (size_t)comp * HH
                                : eb1 + (size_t)(comp - 16) * HH;

  int tid = threadIdx.x, lane = tid & 63, wid = tid >> 6;
  int wm = (wid >> 1) << 6, wn = (wid & 1) << 6;
  int lr = lane & 15, lg = lane >> 4;

  const short* aSrc[4]; const short* bSrc[4]; int ldsOff[4];
#pragma unroll
  for (int q = 0; q < 4; ++q) {
    int gidx = (q * 4 + wid) * 64 + lane, ar = gidx >> 3, sl = gidx & 7;
    aSrc[q] = Ab  + ((size_t)(comp * MP + mt * BM + ar)) * DD + sl * 8;
    bSrc[q] = Wt1 + ((size_t)(comp * HH + nt * BN + ar)) * DD + sl * 8;
    ldsOff[q] = (q * 4 + wid) * 512;
  }

  f32x4 acc[4][4] = {};

  auto stage = [&](int t, int buf) {
    int nb = buf * 8192, off = t * 64;
#pragma unroll
    for (int q = 0; q < 4; ++q) gl_lds16(aSrc[q] + off, smem + nb + ldsOff[q]);
#pragma unroll
    for (int q = 0; q < 4; ++q) gl_lds16(bSrc[q] + off, smem + 16384 + nb + ldsOff[q]);
  };
  auto compute = [&](int buf) {
    const short* A = smem + buf * 8192;
    const short* B = smem + 16384 + buf * 8192;
    __builtin_amdgcn_s_setprio(1);
#pragma unroll
    for (int kk = 0; kk < 2; ++kk) {
      bf16x8 af[4], bf_[4];
#pragma unroll
      for (int i = 0; i < 4; ++i)
        af[i] = *reinterpret_cast<const bf16x8*>(&A[sw(wm + i * 16 + lr, kk * 4 + lg)]);
#pragma unroll
      for (int j = 0; j < 4; ++j)
        bf_[j] = *reinterpret_cast<const bf16x8*>(&B[sw(wn + j * 16 + lr, kk * 4 + lg)]);
#pragma unroll
      for (int i = 0; i < 4; ++i)
#pragma unroll
        for (int j = 0; j < 4; ++j)
          acc[i][j] = __builtin_amdgcn_mfma_f32_16x16x32_bf16(af[i], bf_[j], acc[i][j], 0, 0, 0);
    }
    __builtin_amdgcn_s_setprio(0);
  };

  constexpr int NTILE = DD / BK;   // 32
  stage(0, 0);
  stage(1, 1);
#pragma unroll 1
  for (int t = 0; t < NTILE - 1; ++t) {
    // oldest 8 (tile t) done; tile t+1's 8 stay in flight across the barrier
    asm volatile("s_waitcnt vmcnt(8)" ::: "memory");
    __builtin_amdgcn_sched_barrier(0);
    __builtin_amdgcn_s_barrier();
    compute(t & 1);
    __builtin_amdgcn_s_barrier();          // all readers of buf[t&1] done
    if (t + 2 < NTILE) stage(t + 2, t & 1);
  }
  asm volatile("s_waitcnt vmcnt(0)" ::: "memory");
  __builtin_amdgcn_sched_barrier(0);
  __builtin_amdgcn_s_barrier();
  compute((NTILE - 1) & 1);
  __builtin_amdgcn_s_barrier();            // before epilogue reuses smem

  // epilogue: +b1, exact gelu -> Cs (stride 132), then coalesced
  // PRE-SWIZZLED bf16 h store (so gemm2 can global_load_lds it)
  short* Cs = smem;                        // 128*132 = 16896 shorts
  const float* b1p = b1 + nt * BN;
#pragma unroll
  for (int i = 0; i < 4; ++i)
#pragma unroll
    for (int j = 0; j < 4; ++j) {
      int nl = wn + j * 16 + lr;
      float bias = b1p[nl];
#pragma unroll
      for (int rr = 0; rr < 4; ++rr) {
        int ml = wm + i * 16 + lg * 4 + rr;
        float v = acc[i][j][rr] + bias;
        float ge = 0.5f * v * (1.0f + erff(v * 0.70710678118654752f));
        Cs[ml * 132 + nl] = f2bf(ge);
      }
    }
  __syncthreads();
  short* hrow = hbuf + ((size_t)(comp * MP + mt * BM)) * HH;
#pragma unroll
  for (int q = 0; q < 16; ++q) {
    int gl = q * 256 + tid;
    int r = gl >> 5, gg = gl & 31;         // 32 4-short granules per row
    s16x4 v = *reinterpret_cast<const s16x4*>(&Cs[r * 132 + gg * 4]);
    int dst = (nt * 2 + (gg >> 4)) * 64 + ((((gg >> 1) & 7) ^ swz(r)) << 3) + (gg & 1) * 4;
    *reinterpret_cast<s16x4*>(&hrow[(size_t)r * HH + dst]) = v;
  }
}

// --------------------------- GEMM2: o = h @ W2 + b2, masked seg-reduce -----
__global__ __launch_bounds__(256, 2) void gemm2_kernel(
    const short* __restrict__ hbuf, const int* __restrict__ ridx,
    const float* __restrict__ nb2, const float* __restrict__ eb2,
    const short* __restrict__ Wt2,
    const float* __restrict__ keepf, float* __restrict__ partial) {
  __shared__ short smem[32768];

  constexpr int NWG = NCOMP * MT * NT2;   // 2048
  constexpr int CPX = NWG / 8;
  int b0 = blockIdx.x;
  int lb = (b0 & 7) * CPX + (b0 >> 3);
  int comp = lb / (MT * NT2);
  int rem  = lb % (MT * NT2);
  int mt = rem / NT2, nt = rem % NT2;
  const float* b2 = (comp < 16) ? nb2 + (size_t)comp * CC
                                : eb2 + (size_t)(comp - 16) * CC;

  int tid = threadIdx.x, lane = tid & 63, wid = tid >> 6;
  int wm = (wid >> 1) << 6, wn = (wid & 1) << 6;
  int lr = lane & 15, lg = lane >> 4;

  const short* aSrc[4]; const short* bSrc[4]; int ldsOff[4];
#pragma unroll
  for (int q = 0; q < 4; ++q) {
    int gidx = (q * 4 + wid) * 64 + lane, ar = gidx >> 3, sl = gidx & 7;
    aSrc[q] = hbuf + ((size_t)(comp * MP + mt * BM + ar)) * HH + sl * 8;
    bSrc[q] = Wt2  + ((size_t)(comp * CC + nt * BN + ar)) * HH + sl * 8;
    ldsOff[q] = (q * 4 + wid) * 512;
  }

  f32x4 acc[4][4] = {};

  auto stage = [&](int t, int buf) {
    int nb = buf * 8192, off = t * 64;
#pragma unroll
    for (int q = 0; q < 4; ++q) gl_lds16(aSrc[q] + off, smem + nb + ldsOff[q]);
#pragma unroll
    for (int q = 0; q < 4; ++q) gl_lds16(bSrc[q] + off, smem + 16384 + nb + ldsOff[q]);
  };
  auto compute = [&](int buf) {
    const short* A = smem + buf * 8192;
    const short* B = smem + 16384 + buf * 8192;
    __builtin_amdgcn_s_setprio(1);
#pragma unroll
    for (int kk = 0; kk < 2; ++kk) {
      bf16x8 af[4], bf_[4];
#pragma unroll
      for (int i = 0; i < 4; ++i)
        af[i] = *reinterpret_cast<const bf16x8*>(&A[sw(wm + i * 16 + lr, kk * 4 + lg)]);
#pragma unroll
      for (int j = 0; j < 4; ++j)
        bf_[j] = *reinterpret_cast<const bf16x8*>(&B[sw(wn + j * 16 + lr, kk * 4 + lg)]);
#pragma unroll
      for (int i = 0; i < 4; ++i)
#pragma unroll
        for (int j = 0; j < 4; ++j)
          acc[i][j] = __builtin_amdgcn_mfma_f32_16x16x32_bf16(af[i], bf_[j], acc[i][j], 0, 0, 0);
    }
    __builtin_amdgcn_s_setprio(0);
  };

  constexpr int NTILE = HH / BK;   // 32
  stage(0, 0);
  stage(1, 1);
#pragma unroll 1
  for (int t = 0; t < NTILE - 1; ++t) {
    asm volatile("s_waitcnt vmcnt(8)" ::: "memory");
    __builtin_amdgcn_sched_barrier(0);
    __builtin_amdgcn_s_barrier();
    compute(t & 1);
    __builtin_amdgcn_s_barrier();
    if (t + 2 < NTILE) stage(t + 2, t & 1);
  }
  asm volatile("s_waitcnt vmcnt(0)" ::: "memory");
  __builtin_amdgcn_sched_barrier(0);
  __builtin_amdgcn_s_barrier();
  compute((NTILE - 1) & 1);
  __builtin_amdgcn_s_barrier();

  // epilogue: (+b2) * keep, seg-reduce by timestamp (LDS reused for part[])
  float* part = (float*)smem;              // 2048 floats (8 KB)
  int*   tarr = (int*)(smem + 4096);       // byte 8192, 128 ints
  float* karr = (float*)(smem + 4352);     // byte 8704, 128 floats
  if (tid < BM) {
    int mglob = mt * BM + tid;
    int mi = mglob < LL ? mglob : LL - 1;
    int r2 = ridx[comp * LL + mi];
    tarr[tid] = r2 >> 11;
    karr[tid] = keepf[(comp << 10) + mglob];
  }
  for (int e = tid; e < TT * BN; e += 256) part[e] = 0.0f;
  __syncthreads();
  const float* b2p = b2 + nt * BN;
#pragma unroll
  for (int i = 0; i < 4; ++i)
#pragma unroll
    for (int j = 0; j < 4; ++j) {
      int nl = wn + j * 16 + lr;
      float bias = b2p[nl];
#pragma unroll
      for (int rr = 0; rr < 4; ++rr) {
        int ml = wm + i * 16 + lg * 4 + rr;
        float v = (acc[i][j][rr] + bias) * karr[ml];
        atomicAdd(&part[tarr[ml] * BN + nl], v);
      }
    }
  __syncthreads();
  float* pout = partial + ((size_t)(comp * MT + mt)) * TT * CC + nt * BN;
  for (int e = tid; e < TT * BN; e += 256) {
    int t2 = e >> 7, c = e & 127;
    pout[(size_t)t2 * CC + c] = part[e];
  }
}

// --------------------------- final reduce over m-tiles ---------------------
__global__ void reduce_kernel(const float* __restrict__ partial,
                              float* __restrict__ out) {
  int idx = blockIdx.x * 256 + threadIdx.x;
  int c    = idx & (CC - 1);
  int comp = (idx >> 10) & (NCOMP - 1);
  int t    = idx >> 15;
  float s = 0.0f;
#pragma unroll
  for (int mt = 0; mt < MT; ++mt)
    s += partial[(((size_t)(comp * MT + mt)) * TT + t) * CC + c];
  out[idx] = s * (1.0f / 4096.0f);
}

// ---------------------------------------------------------------------------
extern "C" void kernel_launch(void* const* d_in, const int* in_sizes, int n_in,
                              void* d_out, int out_size, void* d_ws, size_t ws_size,
                              hipStream_t stream) {
  const float* x    = (const float*)d_in[0];
  const int*   ridx = (const int*)d_in[3];
  const float* nW1  = (const float*)d_in[4];
  const float* nb1  = (const float*)d_in[5];
  const float* nW2  = (const float*)d_in[6];
  const float* nb2  = (const float*)d_in[7];
  const float* eW1  = (const float*)d_in[8];
  const float* eb1  = (const float*)d_in[9];
  const float* eW2  = (const float*)d_in[10];
  const float* eb2  = (const float*)d_in[11];
  float* out = (float*)d_out;

  // ws: [h 134MB][bitmap][keep][partial 16MB][Ab/Wt2 134MB][Wt1 268MB] ~554MB
  const size_t H_B   = (size_t)NCOMP * MP * HH * 2;
  const size_t BMP_B = (size_t)NCOMP * 1024 * 4;
  const size_t KP_B  = (size_t)NCOMP * 1024 * 4;
  const size_t PRT_B = (size_t)NCOMP * MT * TT * CC * 4;
  const size_t base  = H_B + BMP_B + KP_B + PRT_B;
  const size_t AB_B  = (size_t)NCOMP * MP * DD * 2;

  char* ws = (char*)d_ws;
  short* hbuf      = (short*)ws;
  unsigned* bitmap = (unsigned*)(ws + H_B);
  float* keepf     = (float*)(ws + H_B + BMP_B);
  float* partial   = (float*)(ws + H_B + BMP_B + KP_B);
  short* Ab        = (short*)(ws + base);            // reused as Wt2 later
  short* Wt1       = (short*)(ws + base + AB_B);

  hipMemsetAsync(bitmap, 0, BMP_B, stream);
  dedup_kernel<<<NCOMP, 256, 0, stream>>>(ridx, bitmap, keepf);
  gather_kernel<<<NCOMP * 128, 256, 0, stream>>>(x, ridx, Ab);
  transW_kernel<<<NCOMP * 32 * 32, 256, 0, stream>>>(nW1, eW1, Wt1, HH, 32);
  gemm1_kernel<<<NCOMP * MT * NT1, 256, 0, stream>>>(nb1, eb1, Ab, Wt1, hbuf);
  transW_kernel<<<NCOMP * 32 * 16, 256, 0, stream>>>(nW2, eW2, Ab, CC, 16);
  gemm2_kernel<<<NCOMP * MT * NT2, 256, 0, stream>>>(hbuf, ridx, nb2, eb2, Ab, keepf, partial);
  reduce_kernel<<<out_size / 256, 256, 0, stream>>>(partial, out);
}